// Round 14
// baseline (1139.626 us; speedup 1.0000x reference)
//
#include <hip/hip_runtime.h>

// ---------------------------------------------------------------------------
// Decoder: out = (tanh(x @ (s1*tern(w1-n1)) + b1)) @ (s2*tern(w2-n2)) + b2
// B=4096, D_IN=1024, D_H=16384, D_OUT=3072
//
// Round-16: gemm2 -> 128x128 tile / 256 threads (4 waves) / 64 KB LDS =
// 2 co-resident blocks per CU (m114 stall overlap), grid 24x32=768.
// r10's failure was 512-thr blocks (2/CU -> 4 waves/SIMD -> 128-VGPR cap ->
// acc spill); 256-thr blocks give 2 waves/SIMD -> 256-reg cap, acc[2][2]
// (~170 total) fits. Schedule = round-13's verified 2-barrier GSTEP scaled
// to 1-chunk (8 KB) halves, 2 loads/stage; FIFO re-traced: enter [P3,P1],
// WA(4) retires P3, WB(4) retires P1, WC(4) retires Q0+Q2; last step
// vmcnt(2)/vmcnt(0). gemm1 + packers unchanged from round-13 (best, 1028us).
//
// Chunk format (8192 B = one 128(m|n) x 32(k) bf16 tile):
//   elem(s, h, lane, e) = T[m = s*32 + (lane&31)][k = h*16 + (lane>>5)*8 + e]
//   flat elem offset = s*1024 + h*512 + lane*8 + e   (s=0..3, h=0..1)
// ---------------------------------------------------------------------------

typedef __bf16 bf16x8 __attribute__((ext_vector_type(8)));
typedef float f32x16 __attribute__((ext_vector_type(16)));

#define AS1 __attribute__((address_space(1)))
#define AS3 __attribute__((address_space(3)))

__device__ __forceinline__ void gload_lds16(const void* g, void* l) {
    __builtin_amdgcn_global_load_lds((AS1 const void*)g, (AS3 void*)l, 16, 0, 0);
}

__device__ __forceinline__ unsigned short f2bf(float f) {
    union { float f; unsigned int u; } v; v.f = f;
    unsigned int u = v.u;
    unsigned int r = u + 0x7fffu + ((u >> 16) & 1u);
    return (unsigned short)(r >> 16);
}

__device__ __forceinline__ unsigned short tern_bf(float q) {
    return (q > 1.f) ? 0x3F80u : ((q < -1.f) ? 0xBF80u : 0u);
}

__device__ __forceinline__ float load_scale(const void* p) {
    int i = *(const int*)p;
    if (i >= -1000000 && i <= 1000000) return (float)i;
    union { int i; float f; } v; v.i = i; return v.f;
}

__device__ __forceinline__ float tanh_fast(float x) {
    float e = __expf(2.0f * x);
    return 1.0f - 2.0f * __builtin_amdgcn_rcpf(e + 1.0f);
}

// ---------------------------------------------------------------------------
// pack_x: x[4096][1024] fp32 -> chunks [mt=32][kt=32][8192B fragment-major]
// ---------------------------------------------------------------------------
__global__ __launch_bounds__(256) void pack_x_kernel(
    const float* __restrict__ x, unsigned short* __restrict__ out)
{
    const int kt = blockIdx.x, mt = blockIdx.y, tid = threadIdx.x;
    unsigned short* chunk = out + (size_t)(mt * 32 + kt) * 4096;
#pragma unroll
    for (int it = 0; it < 2; it++) {
        int g = tid + it * 256;
        int s = g >> 7, r = g & 127, h = (r >> 6) & 1, ln = r & 63;
        int m = s * 32 + (ln & 31), k = h * 16 + (ln >> 5) * 8;
        const float* src = x + (size_t)(mt * 128 + m) * 1024 + kt * 32 + k;
        float4 v0 = *(const float4*)src;
        float4 v1 = *(const float4*)(src + 4);
        unsigned int w0 = (unsigned int)f2bf(v0.x) | ((unsigned int)f2bf(v0.y) << 16);
        unsigned int w1 = (unsigned int)f2bf(v0.z) | ((unsigned int)f2bf(v0.w) << 16);
        unsigned int w2 = (unsigned int)f2bf(v1.x) | ((unsigned int)f2bf(v1.y) << 16);
        unsigned int w3 = (unsigned int)f2bf(v1.z) | ((unsigned int)f2bf(v1.w) << 16);
        uint4 o; o.x = w0; o.y = w1; o.z = w2; o.w = w3;
        *(uint4*)&chunk[(size_t)g * 8] = o;
    }
}

// ---------------------------------------------------------------------------
// quant_pack_w (round-5 form): w,n [K][N] fp32 -> tern bf16 chunks
// [N/128][K/32][8192B]. grid (Kt, N/128), block 256.
// ---------------------------------------------------------------------------
__global__ __launch_bounds__(256) void quant_pack_w(
    const float* __restrict__ w, const float* __restrict__ nz,
    const void* __restrict__ scale_ptr,
    unsigned short* __restrict__ out, int N, int Kt)
{
    __shared__ unsigned short lt[128 * 34];
    const int kt = blockIdx.x, nt = blockIdx.y, tid = threadIdx.x;
    const float scale = load_scale(scale_ptr);
#pragma unroll
    for (int it = 0; it < 4; it++) {
        int p = it * 1024 + tid * 4;
        int kr = p >> 7, nc = p & 127;
        size_t g = (size_t)(kt * 32 + kr) * N + nt * 128 + nc;
        float4 wv = *(const float4*)(w + g);
        float4 nv = *(const float4*)(nz + g);
        lt[(nc + 0) * 34 + kr] = tern_bf(wv.x - scale * nv.x);
        lt[(nc + 1) * 34 + kr] = tern_bf(wv.y - scale * nv.y);
        lt[(nc + 2) * 34 + kr] = tern_bf(wv.z - scale * nv.z);
        lt[(nc + 3) * 34 + kr] = tern_bf(wv.w - scale * nv.w);
    }
    __syncthreads();
    unsigned short* chunk = out + (size_t)(nt * Kt + kt) * 4096;
#pragma unroll
    for (int it = 0; it < 2; it++) {
        int g = tid + it * 256;
        int s = g >> 7, r = g & 127, h = (r >> 6) & 1, ln = r & 63;
        int n = s * 32 + (ln & 31), k = h * 16 + (ln >> 5) * 8;
        const unsigned int* p32 = (const unsigned int*)&lt[n * 34 + k];
        uint4 o; o.x = p32[0]; o.y = p32[1]; o.z = p32[2]; o.w = p32[3];
        *(uint4*)&chunk[(size_t)g * 8] = o;
    }
}

// ---------------------------------------------------------------------------
// Shared sync macros
// ---------------------------------------------------------------------------
#define VMCNT(n) asm volatile("s_waitcnt vmcnt(" #n ")" ::: "memory")
#define BARRIER() { asm volatile("" ::: "memory"); __builtin_amdgcn_s_barrier(); asm volatile("" ::: "memory"); }
#define NOWAIT ((void)0)

// ---- 256^2 template pieces (gemm1, round-13 verified) ---------------------
#define RD_FRAG(dst, HALF, SUB, P)                                            \
    dst[0] = *(const bf16x8*)&lds[P][HALF][(SUB)*1024 + lane*8];              \
    dst[1] = *(const bf16x8*)&lds[P][HALF][(SUB)*1024 + 512 + lane*8];        \
    dst[2] = *(const bf16x8*)&lds[P][HALF][4096 + (SUB)*1024 + lane*8];       \
    dst[3] = *(const bf16x8*)&lds[P][HALF][4096 + (SUB)*1024 + 512 + lane*8];

#define MFMA4(ci, cj, av, bv)                                                 \
    acc[ci][cj] = __builtin_amdgcn_mfma_f32_32x32x16_bf16(av[0], bv[0], acc[ci][cj], 0,0,0); \
    acc[ci][cj] = __builtin_amdgcn_mfma_f32_32x32x16_bf16(av[1], bv[1], acc[ci][cj], 0,0,0); \
    acc[ci][cj] = __builtin_amdgcn_mfma_f32_32x32x16_bf16(av[2], bv[2], acc[ci][cj], 0,0,0); \
    acc[ci][cj] = __builtin_amdgcn_mfma_f32_32x32x16_bf16(av[3], bv[3], acc[ci][cj], 0,0,0);

#define GSTEP(P, Q, T, WA, WB, WC, DO_STAGE)                                  \
  { /* ---- region 1 ---- */                                                  \
    if (DO_STAGE) STAGE(Q, 0, (T) + 1);                                       \
    WA; BARRIER();                                                            \
    RD_FRAG(fa0, 0, sA, P); RD_FRAG(fa1, 0, sA + 1, P);                       \
    RD_FRAG(fb0, 2, sB, P); RD_FRAG(fb1, 3, sB, P);                           \
    __builtin_amdgcn_s_setprio(1);                                            \
    MFMA4(0, 0, fa0, fb0); MFMA4(1, 0, fa1, fb0);                             \
    __builtin_amdgcn_s_setprio(0);                                            \
    if (DO_STAGE) STAGE(Q, 2, (T) + 1);                                       \
    WB;                                                                       \
    __builtin_amdgcn_s_setprio(1);                                            \
    MFMA4(0, 1, fa0, fb1); MFMA4(1, 1, fa1, fb1);                             \
    __builtin_amdgcn_s_setprio(0);                                            \
    /* ---- region 2 ---- */                                                  \
    if (DO_STAGE) STAGE(Q, 3, (T) + 1);                                       \
    BARRIER();                                                                \
    RD_FRAG(fa0, 1, sA, P); RD_FRAG(fa1, 1, sA + 1, P);                       \
    __builtin_amdgcn_s_setprio(1);                                            \
    MFMA4(2, 1, fa0, fb1); MFMA4(3, 1, fa1, fb1);                             \
    __builtin_amdgcn_s_setprio(0);                                            \
    if (DO_STAGE) STAGE(Q, 1, (T) + 1);                                       \
    WC;                                                                       \
    __builtin_amdgcn_s_setprio(1);                                            \
    MFMA4(2, 0, fa0, fb0); MFMA4(3, 0, fa1, fb0);                             \
    __builtin_amdgcn_s_setprio(0);                                            \
  }

// ---- 128^2 template pieces (gemm2, round-16) ------------------------------
// halves: 0 = A chunk 2t, 1 = A chunk 2t+1, 2 = B chunk 2t, 3 = B chunk 2t+1
#define RD2(dst, HALF, SUB, P)                                                \
    dst[0] = *(const bf16x8*)&lds[P][HALF][(SUB)*1024 + lane*8];              \
    dst[1] = *(const bf16x8*)&lds[P][HALF][(SUB)*1024 + 512 + lane*8];

#define MFMA2(ci, cj, av, bv)                                                 \
    acc[ci][cj] = __builtin_amdgcn_mfma_f32_32x32x16_bf16(av[0], bv[0], acc[ci][cj], 0,0,0); \
    acc[ci][cj] = __builtin_amdgcn_mfma_f32_32x32x16_bf16(av[1], bv[1], acc[ci][cj], 0,0,0);

#define GSTEP128(P, Q, T, WA, WB, WC, DO_STAGE)                               \
  { /* ---- region 1: k-chunk 2T (halves 0,2) ---- */                         \
    if (DO_STAGE) STAGE(Q, 0, (T) + 1);                                       \
    WA; BARRIER();                                                            \
    RD2(ga0, 0, sA, P); RD2(ga1, 0, sA + 1, P);                               \
    RD2(gb0, 2, sB, P); RD2(gb1, 2, sB + 1, P);                               \
    __builtin_amdgcn_s_setprio(1);                                            \
    MFMA2(0, 0, ga0, gb0); MFMA2(1, 0, ga1, gb0);                             \
    __builtin_amdgcn_s_setprio(0);                                            \
    if (DO_STAGE) STAGE(Q, 2, (T) + 1);                                       \
    WB;                                                                       \
    __builtin_amdgcn_s_setprio(1);                                            \
    MFMA2(0, 1, ga0, gb1); MFMA2(1, 1, ga1, gb1);                             \
    __builtin_amdgcn_s_setprio(0);                                            \
    /* ---- region 2: k-chunk 2T+1 (halves 1,3) ---- */                       \
    if (DO_STAGE) STAGE(Q, 3, (T) + 1);                                       \
    BARRIER();                                                                \
    RD2(ga0, 1, sA, P); RD2(ga1, 1, sA + 1, P);                               \
    RD2(gb0, 3, sB, P); RD2(gb1, 3, sB + 1, P);                               \
    __builtin_amdgcn_s_setprio(1);                                            \
    MFMA2(0, 0, ga0, gb0); MFMA2(1, 0, ga1, gb0);                             \
    __builtin_amdgcn_s_setprio(0);                                            \
    if (DO_STAGE) STAGE(Q, 1, (T) + 1);                                       \
    WC;                                                                       \
    __builtin_amdgcn_s_setprio(1);                                            \
    MFMA2(0, 1, ga0, gb1); MFMA2(1, 1, ga1, gb1);                             \
    __builtin_amdgcn_s_setprio(0);                                            \
  }

// ---------------------------------------------------------------------------
// GEMM1 (256^2, swapped; round-13 verified): A = w1q, B = xq.
// acc = h^T: k2 over regs, m over lanes == hq chunk layout.
// Grid 16x64 = 1024 blocks; XCD-chunked swizzle (bijective, 1024%8==0).
// ---------------------------------------------------------------------------
__global__ __launch_bounds__(512, 2) void gemm1_256_kernel(
    const unsigned short* __restrict__ Ap,   // w1q chunks [(n1>>7)][kt=32]
    const unsigned short* __restrict__ Bp,   // xq  chunks [(m>>7)][kt=32]
    unsigned short* __restrict__ Hq,
    const float* __restrict__ s1v, const float* __restrict__ b1v)
{
    __shared__ unsigned short lds[2][4][8192];   // 128 KiB
    const int tid = threadIdx.x;
    const int lane = tid & 63, wave = tid >> 6;
    const int bid0 = blockIdx.x + 16 * blockIdx.y;
    const int wg = (bid0 & 7) * 128 + (bid0 >> 3);
    const int NT = wg & 15;        // batch / 256
    const int MT = wg >> 4;        // n1 / 256
    const int wm = ((wave >> 2) & 1) * 64;
    const int sA = wm >> 5;
    const int sB = wave & 3;

    f32x16 acc[4][2] = {};

    const unsigned short* Ab = Ap + ((size_t)(2 * MT) * 32) * 4096;
    const unsigned short* Bb = Bp + ((size_t)(2 * NT) * 32) * 4096;

    auto STAGE = [&](int q, int half, int t) {
        const unsigned short* g = (half < 2)
            ? (Ab + ((size_t)(half * 32 + 2 * t)) * 4096)
            : (Bb + ((size_t)((half - 2) * 32 + 2 * t)) * 4096);
        unsigned short* l = &lds[q][half][0];
        gload_lds16(g + tid * 8,        l + tid * 8);
        gload_lds16(g + 4096 + tid * 8, l + 4096 + tid * 8);
    };

    bf16x8 fa0[4], fa1[4], fb0[4], fb1[4];

    // prologue: stage step-0's 4 halves; first GSTEP supplies vmcnt+barrier
    STAGE(0, 0, 0); STAGE(0, 2, 0); STAGE(0, 3, 0); STAGE(0, 1, 0);

    for (int t = 0; t < 14; t += 2) {
        GSTEP(0, 1, t,     VMCNT(4), VMCNT(4), VMCNT(4), true);
        GSTEP(1, 0, t + 1, VMCNT(4), VMCNT(4), VMCNT(4), true);
    }
    GSTEP(0, 1, 14, VMCNT(4), VMCNT(4), VMCNT(4), true);
    GSTEP(1, 0, 15, VMCNT(2), VMCNT(0), NOWAIT,  false);

    // all waves done with LDS reads before the image overwrite
    __syncthreads();

    // ---- epilogue: tanh + pack into 16-chunk LDS image, then stream out.
    const int mloc = lane & 31, hi = lane >> 5;
    unsigned int* stg32 = (unsigned int*)&lds[0][0][0];
#pragma unroll
    for (int i = 0; i < 4; i++) {
        const int kc  = (i >> 1) * 4 + sA + (i & 1);   // 0..7, disjoint per wm
        const int k2b = MT * 256 + (i >> 1) * 128 + wm + (i & 1) * 32;
#pragma unroll
        for (int j = 0; j < 2; j++) {
#pragma unroll
            for (int c = 0; c < 8; c++) {
                const int n1off = 8 * (c >> 1) + 4 * hi + 2 * (c & 1);
                const int n1g = k2b + n1off;
                float t0 = tanh_fast(s1v[n1g]     * acc[i][j][2 * c]     + b1v[n1g]);
                float t1 = tanh_fast(s1v[n1g + 1] * acc[i][j][2 * c + 1] + b1v[n1g + 1]);
                unsigned int pw = (unsigned int)f2bf(t0)
                                | ((unsigned int)f2bf(t1) << 16);
                const int a32 = (j * 8 + kc) * 2048 + sB * 512
                              + ((c >> 2) & 1) * 256 + ((c >> 1) & 1) * 128
                              + mloc * 4 + 2 * hi + (c & 1);
                stg32[a32] = pw;
            }
        }
    }
    __syncthreads();

    // stream out: per m-group, 8 contiguous chunks = 64 KB = 4096 uint4,
    // image group mg starts at mg*4096 uint4.
#pragma unroll
    for (int mg = 0; mg < 2; mg++) {
        uint4* dst = (uint4*)(Hq + ((size_t)(2 * NT + mg) * 512 + MT * 8) * 4096);
        const uint4* src = (const uint4*)&lds[0][0][0];
#pragma unroll
        for (int it = 0; it < 8; it++)
            dst[it * 512 + tid] = src[mg * 4096 + it * 512 + tid];
    }
}

// ---------------------------------------------------------------------------
// GEMM2 (128^2, 2 blocks/CU): out[m][n] = s2[n]*acc + b2[n].
// 256 thr = 4 waves (2M x 2N); wave tile 64x64 = acc[2][2].
// LDS 64 KB (2 dbuf x 4 halves x 8 KB chunk) -> 2 co-resident blocks/CU.
// Grid 24x32 = 768 blocks; XCD-chunked swizzle (bijective, 768%8==0).
// ---------------------------------------------------------------------------
__global__ __launch_bounds__(256, 2) void gemm2_128_kernel(
    const unsigned short* __restrict__ Ap,   // hq  chunks [mt128][k2t=512]
    const unsigned short* __restrict__ Bp,   // w2q chunks [nt128][k2t=512]
    float* __restrict__ out,
    const float* __restrict__ s2, const float* __restrict__ b2)
{
    __shared__ unsigned short lds[2][4][4096];   // 64 KiB
    const int tid = threadIdx.x;
    const int lane = tid & 63, wave = tid >> 6;
    const int bid0 = blockIdx.x + 24 * blockIdx.y;
    const int wg = (bid0 & 7) * 96 + (bid0 >> 3);
    const int NT = wg % 24;                      // D_OUT/128
    const int MT = wg / 24;                      // B/128
    const int wM = wave >> 1, wN = wave & 1;
    const int sA = wM * 2, sB = wN * 2;

    f32x16 acc[2][2] = {};

    const unsigned short* Ab = Ap + ((size_t)MT * 512) * 4096;
    const unsigned short* Bb = Bp + ((size_t)NT * 512) * 4096;

    // stage one 8 KB chunk; 2 gloads of 256 thr x 16 B
    auto STAGE = [&](int q, int half, int t) {
        const unsigned short* g = (half < 2)
            ? (Ab + ((size_t)(2 * t + half)) * 4096)
            : (Bb + ((size_t)(2 * t + (half - 2))) * 4096);
        unsigned short* l = &lds[q][half][0];
        gload_lds16(g + tid * 8,        l + tid * 8);
        gload_lds16(g + 2048 + tid * 8, l + 2048 + tid * 8);
    };

    bf16x8 ga0[2], ga1[2], gb0[2], gb1[2];

    // prologue: stage step-0's 4 halves (order = steady cadence Q0,Q2,Q3,Q1)
    STAGE(0, 0, 0); STAGE(0, 2, 0); STAGE(0, 3, 0); STAGE(0, 1, 0);

    for (int t = 0; t < 254; t += 2) {
        GSTEP128(0, 1, t,     VMCNT(4), VMCNT(4), VMCNT(4), true);
        GSTEP128(1, 0, t + 1, VMCNT(4), VMCNT(4), VMCNT(4), true);
    }
    GSTEP128(0, 1, 254, VMCNT(4), VMCNT(4), VMCNT(4), true);
    GSTEP128(1, 0, 255, VMCNT(2), VMCNT(0), NOWAIT,  false);

    // epilogue: out[m][n] = s2[n]*acc + b2[n]
    const int l31 = lane & 31;
    const int rowb = 4 * (lane >> 5);
#pragma unroll
    for (int j = 0; j < 2; j++) {
        int n = NT * 128 + wN * 64 + j * 32 + l31;
        float sc = s2[n], bb = b2[n];
#pragma unroll
        for (int i = 0; i < 2; i++) {
            int mbase = MT * 128 + wM * 64 + i * 32;
#pragma unroll
            for (int reg = 0; reg < 16; reg++) {
                int m = mbase + (reg & 3) + 8 * (reg >> 2) + rowb;
                out[(size_t)m * 3072 + n] = sc * acc[i][j][reg] + bb;
            }
        }
    }
}

// ---------------------------------------------------------------------------
extern "C" void kernel_launch(void* const* d_in, const int* in_sizes, int n_in,
                              void* d_out, int out_size, void* d_ws, size_t ws_size,
                              hipStream_t stream) {
    const float* x  = (const float*)d_in[0];   // [4096,1024]
    const float* w1 = (const float*)d_in[1];   // [1024,16384]
    const float* s1 = (const float*)d_in[2];   // [16384]
    const float* b1 = (const float*)d_in[3];   // [16384]
    const float* w2 = (const float*)d_in[4];   // [16384,3072]
    const float* s2 = (const float*)d_in[5];   // [3072]
    const float* b2 = (const float*)d_in[6];   // [3072]
    const float* n1 = (const float*)d_in[7];   // [1024,16384]
    const float* n2 = (const float*)d_in[8];   // [16384,3072]
    const void* scale_p = d_in[9];             // scalar
    float* out = (float*)d_out;

    // workspace layout (MiB offsets): xq 8 | w1q 32 | hq 128 | w2q 96 = 264
    if (ws_size < (264ull << 20)) return;
    unsigned char* ws = (unsigned char*)d_ws;
    unsigned short* xq  = (unsigned short*)(ws);
    unsigned short* w1q = (unsigned short*)(ws + (8ull << 20));
    unsigned short* hq  = (unsigned short*)(ws + (40ull << 20));
    unsigned short* w2q = (unsigned short*)(ws + (168ull << 20));

    // pack/quant
    pack_x_kernel<<<dim3(32, 32), 256, 0, stream>>>(x, xq);
    quant_pack_w<<<dim3(32, 128), 256, 0, stream>>>(w1, n1, scale_p, w1q, 16384, 32);
    quant_pack_w<<<dim3(512, 24), 256, 0, stream>>>(w2, n2, scale_p, w2q, 3072, 512);

    // GEMM1 (256^2 swapped): w1^T[16384x1024] @ x^T[1024x4096] -> hq chunks
    gemm1_256_kernel<<<dim3(16, 64), 512, 0, stream>>>(w1q, xq, hq, s1, b1);
    // GEMM2: 128^2 tile, 2 blocks/CU, 768 blocks
    gemm2_128_kernel<<<dim3(24, 32), 256, 0, stream>>>(hq, w2q, out, s2, b2);
}

// Round 15
// 997.139 us; speedup vs baseline: 1.1429x; 1.1429x over previous
//
#include <hip/hip_runtime.h>

// ---------------------------------------------------------------------------
// Decoder: out = (tanh(x @ (s1*tern(w1-n1)) + b1)) @ (s2*tern(w2-n2)) + b2
// B=4096, D_IN=1024, D_H=16384, D_OUT=3072
//
// Round-17: r14's 128^2 co-residency refuted by counters (FETCH 459MB->1.22GB,
// traffic swamped the fill gain). This round: exact-fill WITHOUT shrinking
// the M-tile: gemm2 = 256x192 tile -> grid 16x16 = 256 blocks = exactly one
// 256-CU round (was 192 = 75%). Per-block work x0.75, LDS 112KB (1 blk/CU).
// B-tile of 192 cols = 3 contiguous 64-col half-chunks (s-major) per k-chunk;
// 3 staging passes are LINEAR in LDS (unit/kc boundaries offset-continuous).
// Waves 4Mx2N, wave tile 64x96 = acc[2][3]. Schedule = r13-verified
// 2-barrier skeleton, FIFO re-derived for 7 loads/step in 4 groups:
//   S1=A(kc0)x2, S2=Bpass0,1, S3=A(kc1)x2, S4=Bpass2
//   W1=vmcnt(3) [retires prev S3], W2=vmcnt(4) [retires prev S4],
//   W3=vmcnt(3) [retires own S1,S2] -> steady invariant [S3(2),S4(1)].
//   Prologue: stage all 4 groups, no wait. Last step: vmcnt(0)/none/none.
// gemm1 + packers byte-identical to round-13 (best, 1028.2us).
//
// Chunk format (8192 B = one 128(m|n) x 32(k) bf16 tile):
//   elem(s, h, lane, e) = T[m = s*32 + (lane&31)][k = h*16 + (lane>>5)*8 + e]
//   flat elem offset = s*1024 + h*512 + lane*8 + e   (s=0..3, h=0..1)
// ---------------------------------------------------------------------------

typedef __bf16 bf16x8 __attribute__((ext_vector_type(8)));
typedef float f32x16 __attribute__((ext_vector_type(16)));

#define AS1 __attribute__((address_space(1)))
#define AS3 __attribute__((address_space(3)))

__device__ __forceinline__ void gload_lds16(const void* g, void* l) {
    __builtin_amdgcn_global_load_lds((AS1 const void*)g, (AS3 void*)l, 16, 0, 0);
}

__device__ __forceinline__ unsigned short f2bf(float f) {
    union { float f; unsigned int u; } v; v.f = f;
    unsigned int u = v.u;
    unsigned int r = u + 0x7fffu + ((u >> 16) & 1u);
    return (unsigned short)(r >> 16);
}

__device__ __forceinline__ unsigned short tern_bf(float q) {
    return (q > 1.f) ? 0x3F80u : ((q < -1.f) ? 0xBF80u : 0u);
}

__device__ __forceinline__ float load_scale(const void* p) {
    int i = *(const int*)p;
    if (i >= -1000000 && i <= 1000000) return (float)i;
    union { int i; float f; } v; v.i = i; return v.f;
}

__device__ __forceinline__ float tanh_fast(float x) {
    float e = __expf(2.0f * x);
    return 1.0f - 2.0f * __builtin_amdgcn_rcpf(e + 1.0f);
}

// ---------------------------------------------------------------------------
// pack_x: x[4096][1024] fp32 -> chunks [mt=32][kt=32][8192B fragment-major]
// ---------------------------------------------------------------------------
__global__ __launch_bounds__(256) void pack_x_kernel(
    const float* __restrict__ x, unsigned short* __restrict__ out)
{
    const int kt = blockIdx.x, mt = blockIdx.y, tid = threadIdx.x;
    unsigned short* chunk = out + (size_t)(mt * 32 + kt) * 4096;
#pragma unroll
    for (int it = 0; it < 2; it++) {
        int g = tid + it * 256;
        int s = g >> 7, r = g & 127, h = (r >> 6) & 1, ln = r & 63;
        int m = s * 32 + (ln & 31), k = h * 16 + (ln >> 5) * 8;
        const float* src = x + (size_t)(mt * 128 + m) * 1024 + kt * 32 + k;
        float4 v0 = *(const float4*)src;
        float4 v1 = *(const float4*)(src + 4);
        unsigned int w0 = (unsigned int)f2bf(v0.x) | ((unsigned int)f2bf(v0.y) << 16);
        unsigned int w1 = (unsigned int)f2bf(v0.z) | ((unsigned int)f2bf(v0.w) << 16);
        unsigned int w2 = (unsigned int)f2bf(v1.x) | ((unsigned int)f2bf(v1.y) << 16);
        unsigned int w3 = (unsigned int)f2bf(v1.z) | ((unsigned int)f2bf(v1.w) << 16);
        uint4 o; o.x = w0; o.y = w1; o.z = w2; o.w = w3;
        *(uint4*)&chunk[(size_t)g * 8] = o;
    }
}

// ---------------------------------------------------------------------------
// quant_pack_w (round-5 form): w,n [K][N] fp32 -> tern bf16 chunks
// [N/128][K/32][8192B]. grid (Kt, N/128), block 256.
// ---------------------------------------------------------------------------
__global__ __launch_bounds__(256) void quant_pack_w(
    const float* __restrict__ w, const float* __restrict__ nz,
    const void* __restrict__ scale_ptr,
    unsigned short* __restrict__ out, int N, int Kt)
{
    __shared__ unsigned short lt[128 * 34];
    const int kt = blockIdx.x, nt = blockIdx.y, tid = threadIdx.x;
    const float scale = load_scale(scale_ptr);
#pragma unroll
    for (int it = 0; it < 4; it++) {
        int p = it * 1024 + tid * 4;
        int kr = p >> 7, nc = p & 127;
        size_t g = (size_t)(kt * 32 + kr) * N + nt * 128 + nc;
        float4 wv = *(const float4*)(w + g);
        float4 nv = *(const float4*)(nz + g);
        lt[(nc + 0) * 34 + kr] = tern_bf(wv.x - scale * nv.x);
        lt[(nc + 1) * 34 + kr] = tern_bf(wv.y - scale * nv.y);
        lt[(nc + 2) * 34 + kr] = tern_bf(wv.z - scale * nv.z);
        lt[(nc + 3) * 34 + kr] = tern_bf(wv.w - scale * nv.w);
    }
    __syncthreads();
    unsigned short* chunk = out + (size_t)(nt * Kt + kt) * 4096;
#pragma unroll
    for (int it = 0; it < 2; it++) {
        int g = tid + it * 256;
        int s = g >> 7, r = g & 127, h = (r >> 6) & 1, ln = r & 63;
        int n = s * 32 + (ln & 31), k = h * 16 + (ln >> 5) * 8;
        const unsigned int* p32 = (const unsigned int*)&lt[n * 34 + k];
        uint4 o; o.x = p32[0]; o.y = p32[1]; o.z = p32[2]; o.w = p32[3];
        *(uint4*)&chunk[(size_t)g * 8] = o;
    }
}

// ---------------------------------------------------------------------------
// Shared sync macros
// ---------------------------------------------------------------------------
#define VMCNT(n) asm volatile("s_waitcnt vmcnt(" #n ")" ::: "memory")
#define BARRIER() { asm volatile("" ::: "memory"); __builtin_amdgcn_s_barrier(); asm volatile("" ::: "memory"); }
#define NOWAIT ((void)0)

// ---- 256^2 template pieces (gemm1, round-13 verified) ---------------------
#define RD_FRAG(dst, HALF, SUB, P)                                            \
    dst[0] = *(const bf16x8*)&lds[P][HALF][(SUB)*1024 + lane*8];              \
    dst[1] = *(const bf16x8*)&lds[P][HALF][(SUB)*1024 + 512 + lane*8];        \
    dst[2] = *(const bf16x8*)&lds[P][HALF][4096 + (SUB)*1024 + lane*8];       \
    dst[3] = *(const bf16x8*)&lds[P][HALF][4096 + (SUB)*1024 + 512 + lane*8];

#define MFMA4(ci, cj, av, bv)                                                 \
    acc[ci][cj] = __builtin_amdgcn_mfma_f32_32x32x16_bf16(av[0], bv[0], acc[ci][cj], 0,0,0); \
    acc[ci][cj] = __builtin_amdgcn_mfma_f32_32x32x16_bf16(av[1], bv[1], acc[ci][cj], 0,0,0); \
    acc[ci][cj] = __builtin_amdgcn_mfma_f32_32x32x16_bf16(av[2], bv[2], acc[ci][cj], 0,0,0); \
    acc[ci][cj] = __builtin_amdgcn_mfma_f32_32x32x16_bf16(av[3], bv[3], acc[ci][cj], 0,0,0);

#define GSTEP(P, Q, T, WA, WB, WC, DO_STAGE)                                  \
  { /* ---- region 1 ---- */                                                  \
    if (DO_STAGE) STAGE(Q, 0, (T) + 1);                                       \
    WA; BARRIER();                                                            \
    RD_FRAG(fa0, 0, sA, P); RD_FRAG(fa1, 0, sA + 1, P);                       \
    RD_FRAG(fb0, 2, sB, P); RD_FRAG(fb1, 3, sB, P);                           \
    __builtin_amdgcn_s_setprio(1);                                            \
    MFMA4(0, 0, fa0, fb0); MFMA4(1, 0, fa1, fb0);                             \
    __builtin_amdgcn_s_setprio(0);                                            \
    if (DO_STAGE) STAGE(Q, 2, (T) + 1);                                       \
    WB;                                                                       \
    __builtin_amdgcn_s_setprio(1);                                            \
    MFMA4(0, 1, fa0, fb1); MFMA4(1, 1, fa1, fb1);                             \
    __builtin_amdgcn_s_setprio(0);                                            \
    /* ---- region 2 ---- */                                                  \
    if (DO_STAGE) STAGE(Q, 3, (T) + 1);                                       \
    BARRIER();                                                                \
    RD_FRAG(fa0, 1, sA, P); RD_FRAG(fa1, 1, sA + 1, P);                       \
    __builtin_amdgcn_s_setprio(1);                                            \
    MFMA4(2, 1, fa0, fb1); MFMA4(3, 1, fa1, fb1);                             \
    __builtin_amdgcn_s_setprio(0);                                            \
    if (DO_STAGE) STAGE(Q, 1, (T) + 1);                                       \
    WC;                                                                       \
    __builtin_amdgcn_s_setprio(1);                                            \
    MFMA4(2, 0, fa0, fb0); MFMA4(3, 0, fa1, fb0);                             \
    __builtin_amdgcn_s_setprio(0);                                            \
  }

// ---------------------------------------------------------------------------
// GEMM1 (256^2, swapped; round-13 verified): A = w1q, B = xq.
// acc = h^T: k2 over regs, m over lanes == hq chunk layout.
// Grid 16x64 = 1024 blocks; XCD-chunked swizzle (bijective, 1024%8==0).
// ---------------------------------------------------------------------------
__global__ __launch_bounds__(512, 2) void gemm1_256_kernel(
    const unsigned short* __restrict__ Ap,   // w1q chunks [(n1>>7)][kt=32]
    const unsigned short* __restrict__ Bp,   // xq  chunks [(m>>7)][kt=32]
    unsigned short* __restrict__ Hq,
    const float* __restrict__ s1v, const float* __restrict__ b1v)
{
    __shared__ unsigned short lds[2][4][8192];   // 128 KiB
    const int tid = threadIdx.x;
    const int lane = tid & 63, wave = tid >> 6;
    const int bid0 = blockIdx.x + 16 * blockIdx.y;
    const int wg = (bid0 & 7) * 128 + (bid0 >> 3);
    const int NT = wg & 15;        // batch / 256
    const int MT = wg >> 4;        // n1 / 256
    const int wm = ((wave >> 2) & 1) * 64;
    const int sA = wm >> 5;
    const int sB = wave & 3;

    f32x16 acc[4][2] = {};

    const unsigned short* Ab = Ap + ((size_t)(2 * MT) * 32) * 4096;
    const unsigned short* Bb = Bp + ((size_t)(2 * NT) * 32) * 4096;

    auto STAGE = [&](int q, int half, int t) {
        const unsigned short* g = (half < 2)
            ? (Ab + ((size_t)(half * 32 + 2 * t)) * 4096)
            : (Bb + ((size_t)((half - 2) * 32 + 2 * t)) * 4096);
        unsigned short* l = &lds[q][half][0];
        gload_lds16(g + tid * 8,        l + tid * 8);
        gload_lds16(g + 4096 + tid * 8, l + 4096 + tid * 8);
    };

    bf16x8 fa0[4], fa1[4], fb0[4], fb1[4];

    // prologue: stage step-0's 4 halves; first GSTEP supplies vmcnt+barrier
    STAGE(0, 0, 0); STAGE(0, 2, 0); STAGE(0, 3, 0); STAGE(0, 1, 0);

    for (int t = 0; t < 14; t += 2) {
        GSTEP(0, 1, t,     VMCNT(4), VMCNT(4), VMCNT(4), true);
        GSTEP(1, 0, t + 1, VMCNT(4), VMCNT(4), VMCNT(4), true);
    }
    GSTEP(0, 1, 14, VMCNT(4), VMCNT(4), VMCNT(4), true);
    GSTEP(1, 0, 15, VMCNT(2), VMCNT(0), NOWAIT,  false);

    // all waves done with LDS reads before the image overwrite
    __syncthreads();

    // ---- epilogue: tanh + pack into 16-chunk LDS image, then stream out.
    const int mloc = lane & 31, hi = lane >> 5;
    unsigned int* stg32 = (unsigned int*)&lds[0][0][0];
#pragma unroll
    for (int i = 0; i < 4; i++) {
        const int kc  = (i >> 1) * 4 + sA + (i & 1);   // 0..7, disjoint per wm
        const int k2b = MT * 256 + (i >> 1) * 128 + wm + (i & 1) * 32;
#pragma unroll
        for (int j = 0; j < 2; j++) {
#pragma unroll
            for (int c = 0; c < 8; c++) {
                const int n1off = 8 * (c >> 1) + 4 * hi + 2 * (c & 1);
                const int n1g = k2b + n1off;
                float t0 = tanh_fast(s1v[n1g]     * acc[i][j][2 * c]     + b1v[n1g]);
                float t1 = tanh_fast(s1v[n1g + 1] * acc[i][j][2 * c + 1] + b1v[n1g + 1]);
                unsigned int pw = (unsigned int)f2bf(t0)
                                | ((unsigned int)f2bf(t1) << 16);
                const int a32 = (j * 8 + kc) * 2048 + sB * 512
                              + ((c >> 2) & 1) * 256 + ((c >> 1) & 1) * 128
                              + mloc * 4 + 2 * hi + (c & 1);
                stg32[a32] = pw;
            }
        }
    }
    __syncthreads();

    // stream out: per m-group, 8 contiguous chunks = 64 KB = 4096 uint4,
    // image group mg starts at mg*4096 uint4.
#pragma unroll
    for (int mg = 0; mg < 2; mg++) {
        uint4* dst = (uint4*)(Hq + ((size_t)(2 * NT + mg) * 512 + MT * 8) * 4096);
        const uint4* src = (const uint4*)&lds[0][0][0];
#pragma unroll
        for (int it = 0; it < 8; it++)
            dst[it * 512 + tid] = src[mg * 4096 + it * 512 + tid];
    }
}

// ---------------------------------------------------------------------------
// GEMM2 (256x192 exact-fill): out[m][n] = s2[n]*acc + b2[n].
// Grid 16x16 = 256 blocks = exactly 1 round; XCD swizzle (256%8==0).
// 8 waves = 4M x 2N; wave tile 64(m) x 96(n) = acc[2][3].
// LDS per buffer: A 32KB (2 chunk-rows x 2 kchunks) + B 24KB (2 kchunks x
// 3 64-col units); x2 buffers = 112 KB. BK=64 (2 k-chunks per step).
// B layout: unit u3 of kchunk kc at Bbase + kc*6144 + u3*2048 (u16);
// staging passes p=0..2: flat f = p*512+tid covers the 12288-u16 B area
// LINEARLY (unit boundaries are offset-continuous).
// ---------------------------------------------------------------------------
__global__ __launch_bounds__(512, 2) void gemm2_192_kernel(
    const unsigned short* __restrict__ Ap,   // hq  chunks [mt128][k2t=512]
    const unsigned short* __restrict__ Bp,   // w2q chunks [nt128][k2t=512]
    float* __restrict__ out,
    const float* __restrict__ s2, const float* __restrict__ b2)
{
    __shared__ unsigned short lds[2][28672];     // 112 KiB: A[0,16384) B[16384,+12288)
    const int tid = threadIdx.x;
    const int lane = tid & 63, wave = tid >> 6;
    const int bid0 = blockIdx.x + 16 * blockIdx.y;
    const int wg = (bid0 & 7) * 32 + (bid0 >> 3);
    const int NT = wg & 15;                      // D_OUT/192
    const int MT = wg >> 4;                      // B/256
    const int wM = wave >> 1;                    // 0..3 (m sub-pair)
    const int wN = wave & 1;                     // 0..1 (n 96-half)

    f32x16 acc[2][3] = {};

    const unsigned short* Abase = Ap + ((size_t)(2 * MT) * 512) * 4096;

    // A stage: one 8 KB chunk (row r, kchunk kc) at LDS kc*8192 + r*4096
    auto STAGE_A = [&](int q, int r, int kc, int t) {
        const unsigned short* g = Abase + ((size_t)(r * 512 + 2 * t + kc)) * 4096;
        unsigned short* l = &lds[q][kc * 8192 + r * 4096];
        gload_lds16(g + tid * 8, l + tid * 8);
    };
    // B stage pass p (8 KB): flat f = p*512+tid; u6 = f>>8 (0..5);
    // kc = u6/3, u3 = u6%3; global 64-col unit u_abs = 3*NT + u3.
    auto STAGE_B = [&](int q, int p, int t) {
        int f = p * 512 + tid;
        int u6 = f >> 8, within = f & 255;
        int kc = (u6 >= 3) ? 1 : 0;
        int u3 = u6 - 3 * kc;
        int u_abs = 3 * NT + u3;
        const unsigned short* g = Bp
            + ((size_t)((u_abs >> 1) * 512 + 2 * t + kc)) * 4096
            + (u_abs & 1) * 2048 + within * 8;
        unsigned short* l = &lds[q][16384 + f * 8];
        gload_lds16(g, l);
    };

    // fragment reads: A sub i (rows wM*64 + i*32), kchunk kc, k-half h in regs
    bf16x8 fa[2][2], fb[3][2];
#define RDA(i, kc, P) {                                                        \
    int sub = 2 * wM + (i);                                                    \
    const unsigned short* a = &lds[P][(kc) * 8192 + (sub >> 2) * 4096          \
                                      + (sub & 3) * 1024 + lane * 8];          \
    fa[i][0] = *(const bf16x8*)a; fa[i][1] = *(const bf16x8*)(a + 512); }
#define RDB(j, kc, P) {                                                        \
    int s = 3 * wN + (j);                                                      \
    const unsigned short* b = &lds[P][16384 + (kc) * 6144 + (s >> 1) * 2048    \
                                      + (s & 1) * 1024 + lane * 8];            \
    fb[j][0] = *(const bf16x8*)b; fb[j][1] = *(const bf16x8*)(b + 512); }
#define MFMA2G(ci, cj)                                                         \
    acc[ci][cj] = __builtin_amdgcn_mfma_f32_32x32x16_bf16(fa[ci][0], fb[cj][0], acc[ci][cj], 0,0,0); \
    acc[ci][cj] = __builtin_amdgcn_mfma_f32_32x32x16_bf16(fa[ci][1], fb[cj][1], acc[ci][cj], 0,0,0);

// per K-step: S1=A(kc0)x2 | W1 | BAR | reads kc0 | 6 MFMA2 (row0) | S2=Bp0,1
// | W2 | 6 MFMA2 (row1)... regions split by kc as in r14's GSTEP128 shape,
// with the wait trace derived in the header comment.
#define GS192(P, Q, T, W1, W2, W3, DO_STAGE)                                   \
  { /* ---- region 1: kchunk 0 ---- */                                         \
    if (DO_STAGE) { STAGE_A(Q, 0, 0, (T) + 1); STAGE_A(Q, 1, 0, (T) + 1); }    \
    W1; BARRIER();                                                             \
    RDA(0, 0, P); RDA(1, 0, P);                                                \
    RDB(0, 0, P); RDB(1, 0, P); RDB(2, 0, P);                                  \
    __builtin_amdgcn_s_setprio(1);                                             \
    MFMA2G(0, 0); MFMA2G(0, 1); MFMA2G(0, 2);                                  \
    __builtin_amdgcn_s_setprio(0);                                             \
    if (DO_STAGE) { STAGE_B(Q, 0, (T) + 1); STAGE_B(Q, 1, (T) + 1); }          \
    W2;                                                                        \
    __builtin_amdgcn_s_setprio(1);                                             \
    MFMA2G(1, 0); MFMA2G(1, 1); MFMA2G(1, 2);                                  \
    __builtin_amdgcn_s_setprio(0);                                             \
    /* ---- region 2: kchunk 1 ---- */                                         \
    if (DO_STAGE) { STAGE_A(Q, 0, 1, (T) + 1); STAGE_A(Q, 1, 1, (T) + 1); }    \
    BARRIER();                                                                 \
    RDA(0, 1, P); RDA(1, 1, P);                                                \
    RDB(0, 1, P); RDB(1, 1, P); RDB(2, 1, P);                                  \
    __builtin_amdgcn_s_setprio(1);                                             \
    MFMA2G(0, 0); MFMA2G(0, 1); MFMA2G(0, 2);                                  \
    __builtin_amdgcn_s_setprio(0);                                             \
    if (DO_STAGE) STAGE_B(Q, 2, (T) + 1);                                      \
    W3;                                                                        \
    __builtin_amdgcn_s_setprio(1);                                             \
    MFMA2G(1, 0); MFMA2G(1, 1); MFMA2G(1, 2);                                  \
    __builtin_amdgcn_s_setprio(0);                                             \
  }

    // prologue: stage step-0's 4 groups (7 loads); first GS192 waits/BARs
    STAGE_A(0, 0, 0, 0); STAGE_A(0, 1, 0, 0);
    STAGE_B(0, 0, 0);    STAGE_B(0, 1, 0);
    STAGE_A(0, 0, 1, 0); STAGE_A(0, 1, 1, 0);
    STAGE_B(0, 2, 0);

    for (int t = 0; t < 254; t += 2) {
        GS192(0, 1, t,     VMCNT(3), VMCNT(4), VMCNT(3), true);
        GS192(1, 0, t + 1, VMCNT(3), VMCNT(4), VMCNT(3), true);
    }
    GS192(0, 1, 254, VMCNT(3), VMCNT(4), VMCNT(3), true);
    GS192(1, 0, 255, VMCNT(0), NOWAIT,   NOWAIT,  false);

    // epilogue: out[m][n] = s2[n]*acc + b2[n]
    const int l31 = lane & 31;
    const int rowb = 4 * (lane >> 5);
#pragma unroll
    for (int j = 0; j < 3; j++) {
        int n = NT * 192 + wN * 96 + j * 32 + l31;
        float sc = s2[n], bb = b2[n];
#pragma unroll
        for (int i = 0; i < 2; i++) {
            int mbase = MT * 256 + wM * 64 + i * 32;
#pragma unroll
            for (int reg = 0; reg < 16; reg++) {
                int m = mbase + (reg & 3) + 8 * (reg >> 2) + rowb;
                out[(size_t)m * 3072 + n] = sc * acc[i][j][reg] + bb;
            }
        }
    }
#undef RDA
#undef RDB
#undef MFMA2G
#undef GS192
}

// ---------------------------------------------------------------------------
extern "C" void kernel_launch(void* const* d_in, const int* in_sizes, int n_in,
                              void* d_out, int out_size, void* d_ws, size_t ws_size,
                              hipStream_t stream) {
    const float* x  = (const float*)d_in[0];   // [4096,1024]
    const float* w1 = (const float*)d_in[1];   // [1024,16384]
    const float* s1 = (const float*)d_in[2];   // [16384]
    const float* b1 = (const float*)d_in[3];   // [16384]
    const float* w2 = (const float*)d_in[4];   // [16384,3072]
    const float* s2 = (const float*)d_in[5];   // [3072]
    const float* b2 = (const float*)d_in[6];   // [3072]
    const float* n1 = (const float*)d_in[7];   // [1024,16384]
    const float* n2 = (const float*)d_in[8];   // [16384,3072]
    const void* scale_p = d_in[9];             // scalar
    float* out = (float*)d_out;

    // workspace layout (MiB offsets): xq 8 | w1q 32 | hq 128 | w2q 96 = 264
    if (ws_size < (264ull << 20)) return;
    unsigned char* ws = (unsigned char*)d_ws;
    unsigned short* xq  = (unsigned short*)(ws);
    unsigned short* w1q = (unsigned short*)(ws + (8ull << 20));
    unsigned short* hq  = (unsigned short*)(ws + (40ull << 20));
    unsigned short* w2q = (unsigned short*)(ws + (168ull << 20));

    // pack/quant
    pack_x_kernel<<<dim3(32, 32), 256, 0, stream>>>(x, xq);
    quant_pack_w<<<dim3(32, 128), 256, 0, stream>>>(w1, n1, scale_p, w1q, 16384, 32);
    quant_pack_w<<<dim3(512, 24), 256, 0, stream>>>(w2, n2, scale_p, w2q, 3072, 512);

    // GEMM1 (256^2 swapped): w1^T[16384x1024] @ x^T[1024x4096] -> hq chunks
    gemm1_256_kernel<<<dim3(16, 64), 512, 0, stream>>>(w1q, xq, hq, s1, b1);
    // GEMM2: 256x192 exact-fill, 256 blocks = 1 round
    gemm2_192_kernel<<<dim3(16, 16), 512, 0, stream>>>(hq, w2q, out, s2, b2);
}

// Round 16
// 969.136 us; speedup vs baseline: 1.1759x; 1.0289x over previous
//
#include <hip/hip_runtime.h>

// ---------------------------------------------------------------------------
// Decoder: out = (tanh(x @ (s1*tern(w1-n1)) + b1)) @ (s2*tern(w2-n2)) + b2
// B=4096, D_IN=1024, D_H=16384, D_OUT=3072
//
// Round-18: single isolated change vs round-15 (best, 997.1us): quant_pack_w
// grid order swapped to nt-fastest (nt = blockIdx.x, kt = blockIdx.y).
// Mechanism: old kt-fastest order made each scheduling round read a COLUMN
// stripe (32 rows x 512B at 12KB stride -> DRAM row-buffer hostile,
// ~2 TB/s effective per the 648us residual budget: packers >= 299us vs
// ~90us floor). nt-fastest makes the co-running blocks of a round read 32
// complete contiguous rows (384KB w2 / 2MB w1 sequential spans).
// Kernel bodies byte-identical; GEMMs byte-identical to round-15.
//
// Chunk format (8192 B = one 128(m|n) x 32(k) bf16 tile):
//   elem(s, h, lane, e) = T[m = s*32 + (lane&31)][k = h*16 + (lane>>5)*8 + e]
//   flat elem offset = s*1024 + h*512 + lane*8 + e   (s=0..3, h=0..1)
// ---------------------------------------------------------------------------

typedef __bf16 bf16x8 __attribute__((ext_vector_type(8)));
typedef float f32x16 __attribute__((ext_vector_type(16)));

#define AS1 __attribute__((address_space(1)))
#define AS3 __attribute__((address_space(3)))

__device__ __forceinline__ void gload_lds16(const void* g, void* l) {
    __builtin_amdgcn_global_load_lds((AS1 const void*)g, (AS3 void*)l, 16, 0, 0);
}

__device__ __forceinline__ unsigned short f2bf(float f) {
    union { float f; unsigned int u; } v; v.f = f;
    unsigned int u = v.u;
    unsigned int r = u + 0x7fffu + ((u >> 16) & 1u);
    return (unsigned short)(r >> 16);
}

__device__ __forceinline__ unsigned short tern_bf(float q) {
    return (q > 1.f) ? 0x3F80u : ((q < -1.f) ? 0xBF80u : 0u);
}

__device__ __forceinline__ float load_scale(const void* p) {
    int i = *(const int*)p;
    if (i >= -1000000 && i <= 1000000) return (float)i;
    union { int i; float f; } v; v.i = i; return v.f;
}

__device__ __forceinline__ float tanh_fast(float x) {
    float e = __expf(2.0f * x);
    return 1.0f - 2.0f * __builtin_amdgcn_rcpf(e + 1.0f);
}

// ---------------------------------------------------------------------------
// pack_x: x[4096][1024] fp32 -> chunks [mt=32][kt=32][8192B fragment-major]
// (kt-fastest is already row-sequential for x: blocks sharing mt read
// consecutive 32-col chunks of the same 128 rows.)
// ---------------------------------------------------------------------------
__global__ __launch_bounds__(256) void pack_x_kernel(
    const float* __restrict__ x, unsigned short* __restrict__ out)
{
    const int kt = blockIdx.x, mt = blockIdx.y, tid = threadIdx.x;
    unsigned short* chunk = out + (size_t)(mt * 32 + kt) * 4096;
#pragma unroll
    for (int it = 0; it < 2; it++) {
        int g = tid + it * 256;
        int s = g >> 7, r = g & 127, h = (r >> 6) & 1, ln = r & 63;
        int m = s * 32 + (ln & 31), k = h * 16 + (ln >> 5) * 8;
        const float* src = x + (size_t)(mt * 128 + m) * 1024 + kt * 32 + k;
        float4 v0 = *(const float4*)src;
        float4 v1 = *(const float4*)(src + 4);
        unsigned int w0 = (unsigned int)f2bf(v0.x) | ((unsigned int)f2bf(v0.y) << 16);
        unsigned int w1 = (unsigned int)f2bf(v0.z) | ((unsigned int)f2bf(v0.w) << 16);
        unsigned int w2 = (unsigned int)f2bf(v1.x) | ((unsigned int)f2bf(v1.y) << 16);
        unsigned int w3 = (unsigned int)f2bf(v1.z) | ((unsigned int)f2bf(v1.w) << 16);
        uint4 o; o.x = w0; o.y = w1; o.z = w2; o.w = w3;
        *(uint4*)&chunk[(size_t)g * 8] = o;
    }
}

// ---------------------------------------------------------------------------
// quant_pack_w (round-5 body; round-18 grid order): w,n [K][N] fp32 ->
// tern bf16 chunks [N/128][K/32][8192B].
// grid (N/128, Kt), block 256 — nt = blockIdx.x (FASTEST), kt = blockIdx.y.
// Co-running blocks of one round now read contiguous full rows.
// ---------------------------------------------------------------------------
__global__ __launch_bounds__(256) void quant_pack_w(
    const float* __restrict__ w, const float* __restrict__ nz,
    const void* __restrict__ scale_ptr,
    unsigned short* __restrict__ out, int N, int Kt)
{
    __shared__ unsigned short lt[128 * 34];
    const int nt = blockIdx.x, kt = blockIdx.y, tid = threadIdx.x;
    const float scale = load_scale(scale_ptr);
#pragma unroll
    for (int it = 0; it < 4; it++) {
        int p = it * 1024 + tid * 4;
        int kr = p >> 7, nc = p & 127;
        size_t g = (size_t)(kt * 32 + kr) * N + nt * 128 + nc;
        float4 wv = *(const float4*)(w + g);
        float4 nv = *(const float4*)(nz + g);
        lt[(nc + 0) * 34 + kr] = tern_bf(wv.x - scale * nv.x);
        lt[(nc + 1) * 34 + kr] = tern_bf(wv.y - scale * nv.y);
        lt[(nc + 2) * 34 + kr] = tern_bf(wv.z - scale * nv.z);
        lt[(nc + 3) * 34 + kr] = tern_bf(wv.w - scale * nv.w);
    }
    __syncthreads();
    unsigned short* chunk = out + (size_t)(nt * Kt + kt) * 4096;
#pragma unroll
    for (int it = 0; it < 2; it++) {
        int g = tid + it * 256;
        int s = g >> 7, r = g & 127, h = (r >> 6) & 1, ln = r & 63;
        int n = s * 32 + (ln & 31), k = h * 16 + (ln >> 5) * 8;
        const unsigned int* p32 = (const unsigned int*)&lt[n * 34 + k];
        uint4 o; o.x = p32[0]; o.y = p32[1]; o.z = p32[2]; o.w = p32[3];
        *(uint4*)&chunk[(size_t)g * 8] = o;
    }
}

// ---------------------------------------------------------------------------
// Shared sync macros
// ---------------------------------------------------------------------------
#define VMCNT(n) asm volatile("s_waitcnt vmcnt(" #n ")" ::: "memory")
#define BARRIER() { asm volatile("" ::: "memory"); __builtin_amdgcn_s_barrier(); asm volatile("" ::: "memory"); }
#define NOWAIT ((void)0)

// ---- 256^2 template pieces (gemm1, round-13 verified) ---------------------
#define RD_FRAG(dst, HALF, SUB, P)                                            \
    dst[0] = *(const bf16x8*)&lds[P][HALF][(SUB)*1024 + lane*8];              \
    dst[1] = *(const bf16x8*)&lds[P][HALF][(SUB)*1024 + 512 + lane*8];        \
    dst[2] = *(const bf16x8*)&lds[P][HALF][4096 + (SUB)*1024 + lane*8];       \
    dst[3] = *(const bf16x8*)&lds[P][HALF][4096 + (SUB)*1024 + 512 + lane*8];

#define MFMA4(ci, cj, av, bv)                                                 \
    acc[ci][cj] = __builtin_amdgcn_mfma_f32_32x32x16_bf16(av[0], bv[0], acc[ci][cj], 0,0,0); \
    acc[ci][cj] = __builtin_amdgcn_mfma_f32_32x32x16_bf16(av[1], bv[1], acc[ci][cj], 0,0,0); \
    acc[ci][cj] = __builtin_amdgcn_mfma_f32_32x32x16_bf16(av[2], bv[2], acc[ci][cj], 0,0,0); \
    acc[ci][cj] = __builtin_amdgcn_mfma_f32_32x32x16_bf16(av[3], bv[3], acc[ci][cj], 0,0,0);

#define GSTEP(P, Q, T, WA, WB, WC, DO_STAGE)                                  \
  { /* ---- region 1 ---- */                                                  \
    if (DO_STAGE) STAGE(Q, 0, (T) + 1);                                       \
    WA; BARRIER();                                                            \
    RD_FRAG(fa0, 0, sA, P); RD_FRAG(fa1, 0, sA + 1, P);                       \
    RD_FRAG(fb0, 2, sB, P); RD_FRAG(fb1, 3, sB, P);                           \
    __builtin_amdgcn_s_setprio(1);                                            \
    MFMA4(0, 0, fa0, fb0); MFMA4(1, 0, fa1, fb0);                             \
    __builtin_amdgcn_s_setprio(0);                                            \
    if (DO_STAGE) STAGE(Q, 2, (T) + 1);                                       \
    WB;                                                                       \
    __builtin_amdgcn_s_setprio(1);                                            \
    MFMA4(0, 1, fa0, fb1); MFMA4(1, 1, fa1, fb1);                             \
    __builtin_amdgcn_s_setprio(0);                                            \
    /* ---- region 2 ---- */                                                  \
    if (DO_STAGE) STAGE(Q, 3, (T) + 1);                                       \
    BARRIER();                                                                \
    RD_FRAG(fa0, 1, sA, P); RD_FRAG(fa1, 1, sA + 1, P);                       \
    __builtin_amdgcn_s_setprio(1);                                            \
    MFMA4(2, 1, fa0, fb1); MFMA4(3, 1, fa1, fb1);                             \
    __builtin_amdgcn_s_setprio(0);                                            \
    if (DO_STAGE) STAGE(Q, 1, (T) + 1);                                       \
    WC;                                                                       \
    __builtin_amdgcn_s_setprio(1);                                            \
    MFMA4(2, 0, fa0, fb0); MFMA4(3, 0, fa1, fb0);                             \
    __builtin_amdgcn_s_setprio(0);                                            \
  }

// ---------------------------------------------------------------------------
// GEMM1 (256^2, swapped; round-13 verified): A = w1q, B = xq.
// acc = h^T: k2 over regs, m over lanes == hq chunk layout.
// Grid 16x64 = 1024 blocks; XCD-chunked swizzle (bijective, 1024%8==0).
// ---------------------------------------------------------------------------
__global__ __launch_bounds__(512, 2) void gemm1_256_kernel(
    const unsigned short* __restrict__ Ap,   // w1q chunks [(n1>>7)][kt=32]
    const unsigned short* __restrict__ Bp,   // xq  chunks [(m>>7)][kt=32]
    unsigned short* __restrict__ Hq,
    const float* __restrict__ s1v, const float* __restrict__ b1v)
{
    __shared__ unsigned short lds[2][4][8192];   // 128 KiB
    const int tid = threadIdx.x;
    const int lane = tid & 63, wave = tid >> 6;
    const int bid0 = blockIdx.x + 16 * blockIdx.y;
    const int wg = (bid0 & 7) * 128 + (bid0 >> 3);
    const int NT = wg & 15;        // batch / 256
    const int MT = wg >> 4;        // n1 / 256
    const int wm = ((wave >> 2) & 1) * 64;
    const int sA = wm >> 5;
    const int sB = wave & 3;

    f32x16 acc[4][2] = {};

    const unsigned short* Ab = Ap + ((size_t)(2 * MT) * 32) * 4096;
    const unsigned short* Bb = Bp + ((size_t)(2 * NT) * 32) * 4096;

    auto STAGE = [&](int q, int half, int t) {
        const unsigned short* g = (half < 2)
            ? (Ab + ((size_t)(half * 32 + 2 * t)) * 4096)
            : (Bb + ((size_t)((half - 2) * 32 + 2 * t)) * 4096);
        unsigned short* l = &lds[q][half][0];
        gload_lds16(g + tid * 8,        l + tid * 8);
        gload_lds16(g + 4096 + tid * 8, l + 4096 + tid * 8);
    };

    bf16x8 fa0[4], fa1[4], fb0[4], fb1[4];

    // prologue: stage step-0's 4 halves; first GSTEP supplies vmcnt+barrier
    STAGE(0, 0, 0); STAGE(0, 2, 0); STAGE(0, 3, 0); STAGE(0, 1, 0);

    for (int t = 0; t < 14; t += 2) {
        GSTEP(0, 1, t,     VMCNT(4), VMCNT(4), VMCNT(4), true);
        GSTEP(1, 0, t + 1, VMCNT(4), VMCNT(4), VMCNT(4), true);
    }
    GSTEP(0, 1, 14, VMCNT(4), VMCNT(4), VMCNT(4), true);
    GSTEP(1, 0, 15, VMCNT(2), VMCNT(0), NOWAIT,  false);

    // all waves done with LDS reads before the image overwrite
    __syncthreads();

    // ---- epilogue: tanh + pack into 16-chunk LDS image, then stream out.
    const int mloc = lane & 31, hi = lane >> 5;
    unsigned int* stg32 = (unsigned int*)&lds[0][0][0];
#pragma unroll
    for (int i = 0; i < 4; i++) {
        const int kc  = (i >> 1) * 4 + sA + (i & 1);   // 0..7, disjoint per wm
        const int k2b = MT * 256 + (i >> 1) * 128 + wm + (i & 1) * 32;
#pragma unroll
        for (int j = 0; j < 2; j++) {
#pragma unroll
            for (int c = 0; c < 8; c++) {
                const int n1off = 8 * (c >> 1) + 4 * hi + 2 * (c & 1);
                const int n1g = k2b + n1off;
                float t0 = tanh_fast(s1v[n1g]     * acc[i][j][2 * c]     + b1v[n1g]);
                float t1 = tanh_fast(s1v[n1g + 1] * acc[i][j][2 * c + 1] + b1v[n1g + 1]);
                unsigned int pw = (unsigned int)f2bf(t0)
                                | ((unsigned int)f2bf(t1) << 16);
                const int a32 = (j * 8 + kc) * 2048 + sB * 512
                              + ((c >> 2) & 1) * 256 + ((c >> 1) & 1) * 128
                              + mloc * 4 + 2 * hi + (c & 1);
                stg32[a32] = pw;
            }
        }
    }
    __syncthreads();

    // stream out: per m-group, 8 contiguous chunks = 64 KB = 4096 uint4,
    // image group mg starts at mg*4096 uint4.
#pragma unroll
    for (int mg = 0; mg < 2; mg++) {
        uint4* dst = (uint4*)(Hq + ((size_t)(2 * NT + mg) * 512 + MT * 8) * 4096);
        const uint4* src = (const uint4*)&lds[0][0][0];
#pragma unroll
        for (int it = 0; it < 8; it++)
            dst[it * 512 + tid] = src[mg * 4096 + it * 512 + tid];
    }
}

// ---------------------------------------------------------------------------
// GEMM2 (256x192 exact-fill; round-15 verified): out = s2[n]*acc + b2[n].
// Grid 16x16 = 256 blocks = exactly 1 round; XCD swizzle (256%8==0).
// 8 waves = 4M x 2N; wave tile 64(m) x 96(n) = acc[2][3]. LDS 112 KB.
// ---------------------------------------------------------------------------
__global__ __launch_bounds__(512, 2) void gemm2_192_kernel(
    const unsigned short* __restrict__ Ap,   // hq  chunks [mt128][k2t=512]
    const unsigned short* __restrict__ Bp,   // w2q chunks [nt128][k2t=512]
    float* __restrict__ out,
    const float* __restrict__ s2, const float* __restrict__ b2)
{
    __shared__ unsigned short lds[2][28672];     // 112 KiB: A[0,16384) B[16384,+12288)
    const int tid = threadIdx.x;
    const int lane = tid & 63, wave = tid >> 6;
    const int bid0 = blockIdx.x + 16 * blockIdx.y;
    const int wg = (bid0 & 7) * 32 + (bid0 >> 3);
    const int NT = wg & 15;                      // D_OUT/192
    const int MT = wg >> 4;                      // B/256
    const int wM = wave >> 1;                    // 0..3 (m sub-pair)
    const int wN = wave & 1;                     // 0..1 (n 96-half)

    f32x16 acc[2][3] = {};

    const unsigned short* Abase = Ap + ((size_t)(2 * MT) * 512) * 4096;

    auto STAGE_A = [&](int q, int r, int kc, int t) {
        const unsigned short* g = Abase + ((size_t)(r * 512 + 2 * t + kc)) * 4096;
        unsigned short* l = &lds[q][kc * 8192 + r * 4096];
        gload_lds16(g + tid * 8, l + tid * 8);
    };
    auto STAGE_B = [&](int q, int p, int t) {
        int f = p * 512 + tid;
        int u6 = f >> 8, within = f & 255;
        int kc = (u6 >= 3) ? 1 : 0;
        int u3 = u6 - 3 * kc;
        int u_abs = 3 * NT + u3;
        const unsigned short* g = Bp
            + ((size_t)((u_abs >> 1) * 512 + 2 * t + kc)) * 4096
            + (u_abs & 1) * 2048 + within * 8;
        unsigned short* l = &lds[q][16384 + f * 8];
        gload_lds16(g, l);
    };

    bf16x8 fa[2][2], fb[3][2];
#define RDA(i, kc, P) {                                                        \
    int sub = 2 * wM + (i);                                                    \
    const unsigned short* a = &lds[P][(kc) * 8192 + (sub >> 2) * 4096          \
                                      + (sub & 3) * 1024 + lane * 8];          \
    fa[i][0] = *(const bf16x8*)a; fa[i][1] = *(const bf16x8*)(a + 512); }
#define RDB(j, kc, P) {                                                        \
    int s = 3 * wN + (j);                                                      \
    const unsigned short* b = &lds[P][16384 + (kc) * 6144 + (s >> 1) * 2048    \
                                      + (s & 1) * 1024 + lane * 8];            \
    fb[j][0] = *(const bf16x8*)b; fb[j][1] = *(const bf16x8*)(b + 512); }
#define MFMA2G(ci, cj)                                                         \
    acc[ci][cj] = __builtin_amdgcn_mfma_f32_32x32x16_bf16(fa[ci][0], fb[cj][0], acc[ci][cj], 0,0,0); \
    acc[ci][cj] = __builtin_amdgcn_mfma_f32_32x32x16_bf16(fa[ci][1], fb[cj][1], acc[ci][cj], 0,0,0);

#define GS192(P, Q, T, W1, W2, W3, DO_STAGE)                                   \
  { /* ---- region 1: kchunk 0 ---- */                                         \
    if (DO_STAGE) { STAGE_A(Q, 0, 0, (T) + 1); STAGE_A(Q, 1, 0, (T) + 1); }    \
    W1; BARRIER();                                                             \
    RDA(0, 0, P); RDA(1, 0, P);                                                \
    RDB(0, 0, P); RDB(1, 0, P); RDB(2, 0, P);                                  \
    __builtin_amdgcn_s_setprio(1);                                             \
    MFMA2G(0, 0); MFMA2G(0, 1); MFMA2G(0, 2);                                  \
    __builtin_amdgcn_s_setprio(0);                                             \
    if (DO_STAGE) { STAGE_B(Q, 0, (T) + 1); STAGE_B(Q, 1, (T) + 1); }          \
    W2;                                                                        \
    __builtin_amdgcn_s_setprio(1);                                             \
    MFMA2G(1, 0); MFMA2G(1, 1); MFMA2G(1, 2);                                  \
    __builtin_amdgcn_s_setprio(0);                                             \
    /* ---- region 2: kchunk 1 ---- */                                         \
    if (DO_STAGE) { STAGE_A(Q, 0, 1, (T) + 1); STAGE_A(Q, 1, 1, (T) + 1); }    \
    BARRIER();                                                                 \
    RDA(0, 1, P); RDA(1, 1, P);                                                \
    RDB(0, 1, P); RDB(1, 1, P); RDB(2, 1, P);                                  \
    __builtin_amdgcn_s_setprio(1);                                             \
    MFMA2G(0, 0); MFMA2G(0, 1); MFMA2G(0, 2);                                  \
    __builtin_amdgcn_s_setprio(0);                                             \
    if (DO_STAGE) STAGE_B(Q, 2, (T) + 1);                                      \
    W3;                                                                        \
    __builtin_amdgcn_s_setprio(1);                                             \
    MFMA2G(1, 0); MFMA2G(1, 1); MFMA2G(1, 2);                                  \
    __builtin_amdgcn_s_setprio(0);                                             \
  }

    // prologue: stage step-0's 4 groups (7 loads); first GS192 waits/BARs
    STAGE_A(0, 0, 0, 0); STAGE_A(0, 1, 0, 0);
    STAGE_B(0, 0, 0);    STAGE_B(0, 1, 0);
    STAGE_A(0, 0, 1, 0); STAGE_A(0, 1, 1, 0);
    STAGE_B(0, 2, 0);

    for (int t = 0; t < 254; t += 2) {
        GS192(0, 1, t,     VMCNT(3), VMCNT(4), VMCNT(3), true);
        GS192(1, 0, t + 1, VMCNT(3), VMCNT(4), VMCNT(3), true);
    }
    GS192(0, 1, 254, VMCNT(3), VMCNT(4), VMCNT(3), true);
    GS192(1, 0, 255, VMCNT(0), NOWAIT,   NOWAIT,  false);

    // epilogue: out[m][n] = s2[n]*acc + b2[n]
    const int l31 = lane & 31;
    const int rowb = 4 * (lane >> 5);
#pragma unroll
    for (int j = 0; j < 3; j++) {
        int n = NT * 192 + wN * 96 + j * 32 + l31;
        float sc = s2[n], bb = b2[n];
#pragma unroll
        for (int i = 0; i < 2; i++) {
            int mbase = MT * 256 + wM * 64 + i * 32;
#pragma unroll
            for (int reg = 0; reg < 16; reg++) {
                int m = mbase + (reg & 3) + 8 * (reg >> 2) + rowb;
                out[(size_t)m * 3072 + n] = sc * acc[i][j][reg] + bb;
            }
        }
    }
#undef RDA
#undef RDB
#undef MFMA2G
#undef GS192
}

// ---------------------------------------------------------------------------
extern "C" void kernel_launch(void* const* d_in, const int* in_sizes, int n_in,
                              void* d_out, int out_size, void* d_ws, size_t ws_size,
                              hipStream_t stream) {
    const float* x  = (const float*)d_in[0];   // [4096,1024]
    const float* w1 = (const float*)d_in[1];   // [1024,16384]
    const float* s1 = (const float*)d_in[2];   // [16384]
    const float* b1 = (const float*)d_in[3];   // [16384]
    const float* w2 = (const float*)d_in[4];   // [16384,3072]
    const float* s2 = (const float*)d_in[5];   // [3072]
    const float* b2 = (const float*)d_in[6];   // [3072]
    const float* n1 = (const float*)d_in[7];   // [1024,16384]
    const float* n2 = (const float*)d_in[8];   // [16384,3072]
    const void* scale_p = d_in[9];             // scalar
    float* out = (float*)d_out;

    // workspace layout (MiB offsets): xq 8 | w1q 32 | hq 128 | w2q 96 = 264
    if (ws_size < (264ull << 20)) return;
    unsigned char* ws = (unsigned char*)d_ws;
    unsigned short* xq  = (unsigned short*)(ws);
    unsigned short* w1q = (unsigned short*)(ws + (8ull << 20));
    unsigned short* hq  = (unsigned short*)(ws + (40ull << 20));
    unsigned short* w2q = (unsigned short*)(ws + (168ull << 20));

    // pack/quant (quant grids now nt-fastest: (N/128, Kt))
    pack_x_kernel<<<dim3(32, 32), 256, 0, stream>>>(x, xq);
    quant_pack_w<<<dim3(128, 32), 256, 0, stream>>>(w1, n1, scale_p, w1q, 16384, 32);
    quant_pack_w<<<dim3(24, 512), 256, 0, stream>>>(w2, n2, scale_p, w2q, 3072, 512);

    // GEMM1 (256^2 swapped): w1^T[16384x1024] @ x^T[1024x4096] -> hq chunks
    gemm1_256_kernel<<<dim3(16, 64), 512, 0, stream>>>(w1q, xq, hq, s1, b1);
    // GEMM2: 256x192 exact-fill, 256 blocks = 1 round
    gemm2_192_kernel<<<dim3(16, 16), 512, 0, stream>>>(hq, w2q, out, s2, b2);
}

// Round 17
// 831.566 us; speedup vs baseline: 1.3705x; 1.1654x over previous
//
#include <hip/hip_runtime.h>

// ---------------------------------------------------------------------------
// Decoder: out = (tanh(x @ (s1*tern(w1-n1)) + b1)) @ (s2*tern(w2-n2)) + b2
// B=4096, D_IN=1024, D_H=16384, D_OUT=3072
//
// Round-19: GEMM2 moved to int8 MFMA (v_mfma_i32_32x32x32_i8). Weights are
// exactly ternary (lossless i8); h=tanh in (-1,1) -> q=rint(127h), output
// error ~0.008 << 0.09 threshold. Per K-step all costs halve: MFMA 24->12,
// stage 56->28KB, LDS reads halve. i8 chunk = 4096B = 128(m|n) x 32(k):
//   byte = s*1024 + lane*16 + e ; elem = T[s*32+(lane&31)][(lane>>5)*16+e]
// (one ds_read_b128 per fragment; staging linear). Wait trace (4 loads/step:
// S1=A kc0, S2=B p0(8KB), S3=A kc1, S4=B p1(4KB dup-load upper waves)):
// W1=vmcnt(3) pre-barrier-1 retires S1,S2(t); W3=vmcnt(3) pre-barrier-2
// retires S3,S4(t); last step vmcnt(2)/vmcnt(0). Scope: gemm2 i8, quant_w2
// i8 emitter (r9 LDS-free shape), gemm1 epilogue emits i8 hq (sample-checked
// mapping). gemm1 core / pack_x / quant_w1 byte-identical to round-16 (969us).
// ---------------------------------------------------------------------------

typedef __bf16 bf16x8 __attribute__((ext_vector_type(8)));
typedef float f32x16 __attribute__((ext_vector_type(16)));
typedef int i32x4 __attribute__((ext_vector_type(4)));
typedef int i32x16 __attribute__((ext_vector_type(16)));

#define AS1 __attribute__((address_space(1)))
#define AS3 __attribute__((address_space(3)))

__device__ __forceinline__ void gload_lds16(const void* g, void* l) {
    __builtin_amdgcn_global_load_lds((AS1 const void*)g, (AS3 void*)l, 16, 0, 0);
}

__device__ __forceinline__ unsigned short f2bf(float f) {
    union { float f; unsigned int u; } v; v.f = f;
    unsigned int u = v.u;
    unsigned int r = u + 0x7fffu + ((u >> 16) & 1u);
    return (unsigned short)(r >> 16);
}

__device__ __forceinline__ unsigned short tern_bf(float q) {
    return (q > 1.f) ? 0x3F80u : ((q < -1.f) ? 0xBF80u : 0u);
}

__device__ __forceinline__ float load_scale(const void* p) {
    int i = *(const int*)p;
    if (i >= -1000000 && i <= 1000000) return (float)i;
    union { int i; float f; } v; v.i = i; return v.f;
}

__device__ __forceinline__ float tanh_fast(float x) {
    float e = __expf(2.0f * x);
    return 1.0f - 2.0f * __builtin_amdgcn_rcpf(e + 1.0f);
}

// ---------------------------------------------------------------------------
// pack_x: x[4096][1024] fp32 -> bf16 chunks [mt=32][kt=32][8192B]
// ---------------------------------------------------------------------------
__global__ __launch_bounds__(256) void pack_x_kernel(
    const float* __restrict__ x, unsigned short* __restrict__ out)
{
    const int kt = blockIdx.x, mt = blockIdx.y, tid = threadIdx.x;
    unsigned short* chunk = out + (size_t)(mt * 32 + kt) * 4096;
#pragma unroll
    for (int it = 0; it < 2; it++) {
        int g = tid + it * 256;
        int s = g >> 7, r = g & 127, h = (r >> 6) & 1, ln = r & 63;
        int m = s * 32 + (ln & 31), k = h * 16 + (ln >> 5) * 8;
        const float* src = x + (size_t)(mt * 128 + m) * 1024 + kt * 32 + k;
        float4 v0 = *(const float4*)src;
        float4 v1 = *(const float4*)(src + 4);
        unsigned int w0 = (unsigned int)f2bf(v0.x) | ((unsigned int)f2bf(v0.y) << 16);
        unsigned int w1 = (unsigned int)f2bf(v0.z) | ((unsigned int)f2bf(v0.w) << 16);
        unsigned int w2 = (unsigned int)f2bf(v1.x) | ((unsigned int)f2bf(v1.y) << 16);
        unsigned int w3 = (unsigned int)f2bf(v1.z) | ((unsigned int)f2bf(v1.w) << 16);
        uint4 o; o.x = w0; o.y = w1; o.z = w2; o.w = w3;
        *(uint4*)&chunk[(size_t)g * 8] = o;
    }
}

// ---------------------------------------------------------------------------
// quant_pack_w (bf16, for w1; round-16 form): grid (N/128, Kt) nt-fastest.
// ---------------------------------------------------------------------------
__global__ __launch_bounds__(256) void quant_pack_w(
    const float* __restrict__ w, const float* __restrict__ nz,
    const void* __restrict__ scale_ptr,
    unsigned short* __restrict__ out, int N, int Kt)
{
    __shared__ unsigned short lt[128 * 34];
    const int nt = blockIdx.x, kt = blockIdx.y, tid = threadIdx.x;
    const float scale = load_scale(scale_ptr);
#pragma unroll
    for (int it = 0; it < 4; it++) {
        int p = it * 1024 + tid * 4;
        int kr = p >> 7, nc = p & 127;
        size_t g = (size_t)(kt * 32 + kr) * N + nt * 128 + nc;
        float4 wv = *(const float4*)(w + g);
        float4 nv = *(const float4*)(nz + g);
        lt[(nc + 0) * 34 + kr] = tern_bf(wv.x - scale * nv.x);
        lt[(nc + 1) * 34 + kr] = tern_bf(wv.y - scale * nv.y);
        lt[(nc + 2) * 34 + kr] = tern_bf(wv.z - scale * nv.z);
        lt[(nc + 3) * 34 + kr] = tern_bf(wv.w - scale * nv.w);
    }
    __syncthreads();
    unsigned short* chunk = out + (size_t)(nt * Kt + kt) * 4096;
#pragma unroll
    for (int it = 0; it < 2; it++) {
        int g = tid + it * 256;
        int s = g >> 7, r = g & 127, h = (r >> 6) & 1, ln = r & 63;
        int n = s * 32 + (ln & 31), k = h * 16 + (ln >> 5) * 8;
        const unsigned int* p32 = (const unsigned int*)&lt[n * 34 + k];
        uint4 o; o.x = p32[0]; o.y = p32[1]; o.z = p32[2]; o.w = p32[3];
        *(uint4*)&chunk[(size_t)g * 8] = o;
    }
}

// ---------------------------------------------------------------------------
// quant_pack_w2_i8: w2,n2 [16384][3072] fp32 -> tern i8 chunks
// [nt=24][k2c=512][4096B]. Each thread: 4n x 8k (r9-verified shape).
// i8 chunk byte = (nl>>5)*1024 + (hi*32 + (nl&31))*16 + e, hi=k>=16.
// grid (24, 256) nt-fastest; c=tid>>7 picks kt within pair.
// ---------------------------------------------------------------------------
__global__ __launch_bounds__(256) void quant_pack_w2_i8(
    const float* __restrict__ w, const float* __restrict__ nz,
    const void* __restrict__ scale_ptr, unsigned char* __restrict__ out)
{
    const int nt = blockIdx.x, ktp = blockIdx.y, tid = threadIdx.x;
    const int c = tid >> 7, r = tid & 127, ng = r & 31, kg = r >> 5;
    const int kt = ktp * 2 + c;
    const float scale = load_scale(scale_ptr);
    const int k0 = kt * 32 + kg * 8;
    const int n0 = nt * 128 + ng * 4;

    int us[8][4];
#pragma unroll
    for (int i = 0; i < 8; i++) {
        size_t g = (size_t)(k0 + i) * 3072 + n0;
        float4 wv = *(const float4*)(w + g);
        float4 nv = *(const float4*)(nz + g);
        float q0 = wv.x - scale * nv.x, q1 = wv.y - scale * nv.y;
        float q2 = wv.z - scale * nv.z, q3 = wv.w - scale * nv.w;
        us[i][0] = (q0 > 1.f) - (q0 < -1.f);
        us[i][1] = (q1 > 1.f) - (q1 < -1.f);
        us[i][2] = (q2 > 1.f) - (q2 < -1.f);
        us[i][3] = (q3 > 1.f) - (q3 < -1.f);
    }

    unsigned char* chunk = out + (size_t)(nt * 512 + kt) * 4096;
    const int hi = kg >> 1, eb = (kg & 1) * 8;
#pragma unroll
    for (int j = 0; j < 4; j++) {
        int nl = ng * 4 + j;
        int addr = (nl >> 5) * 1024 + (hi * 32 + (nl & 31)) * 16 + eb;
        unsigned int lo = (us[0][j] & 255) | ((us[1][j] & 255) << 8)
                        | ((us[2][j] & 255) << 16) | ((us[3][j] & 255) << 24);
        unsigned int hw = (us[4][j] & 255) | ((us[5][j] & 255) << 8)
                        | ((us[6][j] & 255) << 16) | ((us[7][j] & 255) << 24);
        uint2 o; o.x = lo; o.y = hw;
        *(uint2*)&chunk[addr] = o;
    }
}

// ---------------------------------------------------------------------------
// Shared sync macros
// ---------------------------------------------------------------------------
#define VMCNT(n) asm volatile("s_waitcnt vmcnt(" #n ")" ::: "memory")
#define BARRIER() { asm volatile("" ::: "memory"); __builtin_amdgcn_s_barrier(); asm volatile("" ::: "memory"); }
#define NOWAIT ((void)0)

// ---- 256^2 bf16 template pieces (gemm1 core, round-13 verified) -----------
#define RD_FRAG(dst, HALF, SUB, P)                                            \
    dst[0] = *(const bf16x8*)&lds[P][HALF][(SUB)*1024 + lane*8];              \
    dst[1] = *(const bf16x8*)&lds[P][HALF][(SUB)*1024 + 512 + lane*8];        \
    dst[2] = *(const bf16x8*)&lds[P][HALF][4096 + (SUB)*1024 + lane*8];       \
    dst[3] = *(const bf16x8*)&lds[P][HALF][4096 + (SUB)*1024 + 512 + lane*8];

#define MFMA4(ci, cj, av, bv)                                                 \
    acc[ci][cj] = __builtin_amdgcn_mfma_f32_32x32x16_bf16(av[0], bv[0], acc[ci][cj], 0,0,0); \
    acc[ci][cj] = __builtin_amdgcn_mfma_f32_32x32x16_bf16(av[1], bv[1], acc[ci][cj], 0,0,0); \
    acc[ci][cj] = __builtin_amdgcn_mfma_f32_32x32x16_bf16(av[2], bv[2], acc[ci][cj], 0,0,0); \
    acc[ci][cj] = __builtin_amdgcn_mfma_f32_32x32x16_bf16(av[3], bv[3], acc[ci][cj], 0,0,0);

#define GSTEP(P, Q, T, WA, WB, WC, DO_STAGE)                                  \
  { if (DO_STAGE) STAGE(Q, 0, (T) + 1);                                       \
    WA; BARRIER();                                                            \
    RD_FRAG(fa0, 0, sA, P); RD_FRAG(fa1, 0, sA + 1, P);                       \
    RD_FRAG(fb0, 2, sB, P); RD_FRAG(fb1, 3, sB, P);                           \
    __builtin_amdgcn_s_setprio(1);                                            \
    MFMA4(0, 0, fa0, fb0); MFMA4(1, 0, fa1, fb0);                             \
    __builtin_amdgcn_s_setprio(0);                                            \
    if (DO_STAGE) STAGE(Q, 2, (T) + 1);                                       \
    WB;                                                                       \
    __builtin_amdgcn_s_setprio(1);                                            \
    MFMA4(0, 1, fa0, fb1); MFMA4(1, 1, fa1, fb1);                             \
    __builtin_amdgcn_s_setprio(0);                                            \
    if (DO_STAGE) STAGE(Q, 3, (T) + 1);                                       \
    BARRIER();                                                                \
    RD_FRAG(fa0, 1, sA, P); RD_FRAG(fa1, 1, sA + 1, P);                       \
    __builtin_amdgcn_s_setprio(1);                                            \
    MFMA4(2, 1, fa0, fb1); MFMA4(3, 1, fa1, fb1);                             \
    __builtin_amdgcn_s_setprio(0);                                            \
    if (DO_STAGE) STAGE(Q, 1, (T) + 1);                                       \
    WC;                                                                       \
    __builtin_amdgcn_s_setprio(1);                                            \
    MFMA4(2, 0, fa0, fb0); MFMA4(3, 0, fa1, fb0);                             \
    __builtin_amdgcn_s_setprio(0);                                            \
  }

// ---------------------------------------------------------------------------
// GEMM1 (256^2, swapped, bf16 core; round-13 verified): A = w1q, B = xq.
// acc = h^T: k2 over regs, m over lanes. Epilogue now emits i8 hq:
// q = rint(127*tanh), packed to a 64 KB LDS chunk image, streamed out.
// Grid 16x64 = 1024 blocks; XCD-chunked swizzle.
// ---------------------------------------------------------------------------
__global__ __launch_bounds__(512, 2) void gemm1_256_kernel(
    const unsigned short* __restrict__ Ap,   // w1q chunks [(n1>>7)][kt=32]
    const unsigned short* __restrict__ Bp,   // xq  chunks [(m>>7)][kt=32]
    unsigned char* __restrict__ Hq,          // i8 chunks [m128][k2c=512] 4KB
    const float* __restrict__ s1v, const float* __restrict__ b1v)
{
    __shared__ unsigned short lds[2][4][8192];   // 128 KiB
    const int tid = threadIdx.x;
    const int lane = tid & 63, wave = tid >> 6;
    const int bid0 = blockIdx.x + 16 * blockIdx.y;
    const int wg = (bid0 & 7) * 128 + (bid0 >> 3);
    const int NT = wg & 15;        // batch / 256
    const int MT = wg >> 4;        // n1 / 256
    const int wm = ((wave >> 2) & 1) * 64;
    const int sA = wm >> 5;
    const int sB = wave & 3;

    f32x16 acc[4][2] = {};

    const unsigned short* Ab = Ap + ((size_t)(2 * MT) * 32) * 4096;
    const unsigned short* Bb = Bp + ((size_t)(2 * NT) * 32) * 4096;

    auto STAGE = [&](int q, int half, int t) {
        const unsigned short* g = (half < 2)
            ? (Ab + ((size_t)(half * 32 + 2 * t)) * 4096)
            : (Bb + ((size_t)((half - 2) * 32 + 2 * t)) * 4096);
        unsigned short* l = &lds[q][half][0];
        gload_lds16(g + tid * 8,        l + tid * 8);
        gload_lds16(g + 4096 + tid * 8, l + 4096 + tid * 8);
    };

    bf16x8 fa0[4], fa1[4], fb0[4], fb1[4];

    STAGE(0, 0, 0); STAGE(0, 2, 0); STAGE(0, 3, 0); STAGE(0, 1, 0);

    for (int t = 0; t < 14; t += 2) {
        GSTEP(0, 1, t,     VMCNT(4), VMCNT(4), VMCNT(4), true);
        GSTEP(1, 0, t + 1, VMCNT(4), VMCNT(4), VMCNT(4), true);
    }
    GSTEP(0, 1, 14, VMCNT(4), VMCNT(4), VMCNT(4), true);
    GSTEP(1, 0, 15, VMCNT(2), VMCNT(0), NOWAIT,  false);

    __syncthreads();

    // ---- epilogue: q = rint(127*tanh(s1*acc+b1)) -> i8 chunk image (64 KB)
    // word addr = (j*8+kc)*1024 + sB*256 + (g>>1)*128 + mloc*4 + (g&1)*2 + hi
    // packs regs 4g..4g+3 (k2off = rr + 8g + 4hi).
    const int mloc = lane & 31, hi = lane >> 5;
    unsigned int* stg32 = (unsigned int*)&lds[0][0][0];
#pragma unroll
    for (int i = 0; i < 4; i++) {
        const int kc  = (i >> 1) * 4 + sA + (i & 1);   // 0..7, disjoint per wm
        const int k2b = MT * 256 + (i >> 1) * 128 + wm + (i & 1) * 32;
#pragma unroll
        for (int j = 0; j < 2; j++) {
#pragma unroll
            for (int g = 0; g < 4; g++) {
                unsigned int pw = 0;
#pragma unroll
                for (int rr = 0; rr < 4; rr++) {
                    const int n1g = k2b + rr + 8 * g + 4 * hi;
                    float t = tanh_fast(s1v[n1g] * acc[i][j][4 * g + rr] + b1v[n1g]);
                    int q = __float2int_rn(t * 127.0f);
                    pw |= ((unsigned int)(q & 255)) << (8 * rr);
                }
                const int w32 = (j * 8 + kc) * 1024 + sB * 256 + (g >> 1) * 128
                              + mloc * 4 + (g & 1) * 2 + hi;
                stg32[w32] = pw;
            }
        }
    }
    __syncthreads();

    // stream out: per m-group, 8 contiguous 4KB chunks = 32 KB = 2048 uint4
#pragma unroll
    for (int mg = 0; mg < 2; mg++) {
        uint4* dst = (uint4*)(Hq + ((size_t)((2 * NT + mg) * 512 + MT * 8)) * 4096);
        const uint4* src = (const uint4*)&lds[0][0][0];
#pragma unroll
        for (int it = 0; it < 4; it++)
            dst[it * 512 + tid] = src[mg * 2048 + it * 512 + tid];
    }
}

// ---------------------------------------------------------------------------
// GEMM2 (256x192, i8): out[m][n] = s2[n]*acc_i32/127 + b2[n].
// Grid 16x16 = 256 blocks (exact fill); XCD swizzle. 8 waves = 4M x 2N;
// wave tile 64 x 96 = acc[2][3] (i32x16). LDS/buffer: A 16 KB (2kc x 2r x
// 4KB) + B 12 KB (2kc x 3 units x 2KB... 6144B/kc) = 28 KB; x2 = 56 KB.
// 4 loads/step: S1=A kc0, S2=B pass0 (8KB), S3=A kc1, S4=B pass1 (4KB,
// upper waves duplicate lower). W1=vmcnt(3) pre-bar1, W3=vmcnt(3) pre-bar2;
// last step vmcnt(2)/vmcnt(0).
// ---------------------------------------------------------------------------
__global__ __launch_bounds__(512, 2) void gemm2_192_i8(
    const unsigned char* __restrict__ Ap,   // hq  i8 chunks [m128][k2c=512]
    const unsigned char* __restrict__ Bp,   // w2q i8 chunks [n128][k2c=512]
    float* __restrict__ out,
    const float* __restrict__ s2, const float* __restrict__ b2)
{
    __shared__ unsigned char lds[2][28672];  // A [0,16384) B [16384,28672)
    const int tid = threadIdx.x;
    const int lane = tid & 63, wave = tid >> 6;
    const int bid0 = blockIdx.x + 16 * blockIdx.y;
    const int wg = (bid0 & 7) * 32 + (bid0 >> 3);
    const int NT = wg & 15;                  // D_OUT/192
    const int MT = wg >> 4;                  // B/256
    const int wM = wave >> 1, wN = wave & 1;

    i32x16 acc[2][3] = {};

    const unsigned char* Abase = Ap + ((size_t)(2 * MT) * 512) * 4096;
    const int ar = tid >> 8, aw = (tid & 255) * 16;

    // B per-thread source offsets (affine in t: +8192 bytes/step)
    auto boff = [&](int f) -> size_t {
        int kc = (f >= 384);
        int rem = f * 16 - kc * 6144;
        int u = rem >> 11, wi = rem & 2047;
        int uab = 3 * NT + u;
        return ((size_t)((uab >> 1) * 512 + kc)) * 4096 + (uab & 1) * 2048 + wi;
    };
    const size_t b0o = boff(tid);
    const size_t b1o = boff(512 + (tid & 255));
    const int b0d = 16384 + tid * 16;
    const int b1d = 16384 + (512 + (tid & 255)) * 16;

    auto STAGE_A = [&](int q, int kc, int t) {
        gload_lds16(Abase + ((size_t)(ar * 512 + kc)) * 4096 + aw + (size_t)t * 8192,
                    &lds[q][kc * 8192 + ar * 4096 + aw]);
    };
    auto STAGE_B0 = [&](int q, int t) {
        gload_lds16(Bp + b0o + (size_t)t * 8192, &lds[q][b0d]);
    };
    auto STAGE_B1 = [&](int q, int t) {
        gload_lds16(Bp + b1o + (size_t)t * 8192, &lds[q][b1d]);
    };

    i32x4 fa[2], fb[3];
#define RDA8(i, kc, P) {                                                       \
    int sub = 2 * wM + (i);                                                    \
    fa[i] = *(const i32x4*)&lds[P][(kc) * 8192 + (sub >> 2) * 4096             \
                                   + (sub & 3) * 1024 + lane * 16]; }
#define RDB8(j, kc, P)                                                         \
    fb[j] = *(const i32x4*)&lds[P][16384 + (kc) * 6144 + (3 * wN + (j)) * 1024 \
                                   + lane * 16];
#define MFMA8(ci, cj)                                                          \
    acc[ci][cj] = __builtin_amdgcn_mfma_i32_32x32x32_i8(fa[ci], fb[cj], acc[ci][cj], 0, 0, 0);

#define GS8(P, Q, T, W1, W3, DO_STAGE)                                         \
  { if (DO_STAGE) STAGE_A(Q, 0, (T) + 1);                                      \
    W1; BARRIER();                                                             \
    RDA8(0, 0, P); RDA8(1, 0, P);                                              \
    RDB8(0, 0, P); RDB8(1, 0, P); RDB8(2, 0, P);                               \
    __builtin_amdgcn_s_setprio(1);                                             \
    MFMA8(0, 0); MFMA8(0, 1); MFMA8(0, 2);                                     \
    __builtin_amdgcn_s_setprio(0);                                             \
    if (DO_STAGE) STAGE_B0(Q, (T) + 1);                                        \
    __builtin_amdgcn_s_setprio(1);                                             \
    MFMA8(1, 0); MFMA8(1, 1); MFMA8(1, 2);                                     \
    __builtin_amdgcn_s_setprio(0);                                             \
    if (DO_STAGE) STAGE_A(Q, 1, (T) + 1);                                      \
    W3; BARRIER();                                                             \
    RDA8(0, 1, P); RDA8(1, 1, P);                                              \
    RDB8(0, 1, P); RDB8(1, 1, P); RDB8(2, 1, P);                               \
    __builtin_amdgcn_s_setprio(1);                                             \
    MFMA8(0, 0); MFMA8(0, 1); MFMA8(0, 2);                                     \
    __builtin_amdgcn_s_setprio(0);                                             \
    if (DO_STAGE) STAGE_B1(Q, (T) + 1);                                        \
    __builtin_amdgcn_s_setprio(1);                                             \
    MFMA8(1, 0); MFMA8(1, 1); MFMA8(1, 2);                                     \
    __builtin_amdgcn_s_setprio(0);                                             \
  }

    // prologue: stage step-0's 4 groups
    STAGE_A(0, 0, 0); STAGE_B0(0, 0); STAGE_A(0, 1, 0); STAGE_B1(0, 0);

    for (int t = 0; t < 254; t += 2) {
        GS8(0, 1, t,     VMCNT(3), VMCNT(3), true);
        GS8(1, 0, t + 1, VMCNT(3), VMCNT(3), true);
    }
    GS8(0, 1, 254, VMCNT(3), VMCNT(3), true);
    GS8(1, 0, 255, VMCNT(2), VMCNT(0), false);

    // epilogue: out = s2[n] * acc/127 + b2[n]
    const int l31 = lane & 31;
    const int rowb = 4 * (lane >> 5);
#pragma unroll
    for (int j = 0; j < 3; j++) {
        int n = NT * 192 + wN * 96 + j * 32 + l31;
        float sc = s2[n] * (1.0f / 127.0f), bb = b2[n];
#pragma unroll
        for (int i = 0; i < 2; i++) {
            int mbase = MT * 256 + wM * 64 + i * 32;
#pragma unroll
            for (int reg = 0; reg < 16; reg++) {
                int m = mbase + (reg & 3) + 8 * (reg >> 2) + rowb;
                out[(size_t)m * 3072 + n] = sc * (float)acc[i][j][reg] + bb;
            }
        }
    }
#undef RDA8
#undef RDB8
#undef MFMA8
#undef GS8
}

// ---------------------------------------------------------------------------
extern "C" void kernel_launch(void* const* d_in, const int* in_sizes, int n_in,
                              void* d_out, int out_size, void* d_ws, size_t ws_size,
                              hipStream_t stream) {
    const float* x  = (const float*)d_in[0];   // [4096,1024]
    const float* w1 = (const float*)d_in[1];   // [1024,16384]
    const float* s1 = (const float*)d_in[2];   // [16384]
    const float* b1 = (const float*)d_in[3];   // [16384]
    const float* w2 = (const float*)d_in[4];   // [16384,3072]
    const float* s2 = (const float*)d_in[5];   // [3072]
    const float* b2 = (const float*)d_in[6];   // [3072]
    const float* n1 = (const float*)d_in[7];   // [1024,16384]
    const float* n2 = (const float*)d_in[8];   // [16384,3072]
    const void* scale_p = d_in[9];             // scalar
    float* out = (float*)d_out;

    // workspace (MiB offsets): xq 8 @0 | w1q 32 @8 | hq-i8 64 @40 | w2q-i8 48 @104
    if (ws_size < (264ull << 20)) return;
    unsigned char* ws = (unsigned char*)d_ws;
    unsigned short* xq  = (unsigned short*)(ws);
    unsigned short* w1q = (unsigned short*)(ws + (8ull << 20));
    unsigned char*  hq  = (unsigned char*)(ws + (40ull << 20));
    unsigned char*  w2q = (unsigned char*)(ws + (104ull << 20));

    // pack/quant
    pack_x_kernel<<<dim3(32, 32), 256, 0, stream>>>(x, xq);
    quant_pack_w<<<dim3(128, 32), 256, 0, stream>>>(w1, n1, scale_p, w1q, 16384, 32);
    quant_pack_w2_i8<<<dim3(24, 256), 256, 0, stream>>>(w2, n2, scale_p, w2q);

    // GEMM1 (bf16 core, i8 hq out)
    gemm1_256_kernel<<<dim3(16, 64), 512, 0, stream>>>(w1q, xq, hq, s1, b1);
    // GEMM2 (i8): 256x192 exact-fill
    gemm2_192_i8<<<dim3(16, 16), 512, 0, stream>>>(hq, w2q, out, s2, b2);
}